// Round 7
// baseline (135.284 us; speedup 1.0000x reference)
//
#include <hip/hip_runtime.h>
#include <hip/hip_bf16.h>
#include <stdint.h>

typedef __attribute__((ext_vector_type(8))) short short8;
typedef __attribute__((ext_vector_type(4))) float f32x4;

#define N_HEADS 12
#define HD      64
#define BSZ     8
#define TSZ     1024
#define CSZ     768
#define MSZ     (BSZ * TSZ)   /* 8192 */
#define N3      (3 * CSZ)     /* 2304 */
#define LDA     72            /* padded LDS stride for attn S-tile */

static __device__ __forceinline__ unsigned short f2bf(float f) {
    union { float f; uint32_t u; } v; v.f = f;
    uint32_t r = v.u + 0x7fffu + ((v.u >> 16) & 1u);
    return (unsigned short)(r >> 16);
}

// async global->LDS, 16B per lane, LDS dest = wave-uniform base + lane*16
static __device__ __forceinline__ void gload16(const unsigned short* g,
                                               unsigned short* l) {
    __builtin_amdgcn_global_load_lds(
        (const __attribute__((address_space(1))) void*)g,
        (__attribute__((address_space(3))) void*)l, 16, 0, 0);
}

// ---------------- fp32 -> bf16 conversion ----------------
__global__ void cvt_f32_to_bf16(const float* __restrict__ s,
                                unsigned short* __restrict__ d, int n) {
    int i = (blockIdx.x * blockDim.x + threadIdx.x) * 4;
    if (i + 3 < n) {
        float4 f = *reinterpret_cast<const float4*>(s + i);
        ushort4 u;
        u.x = f2bf(f.x); u.y = f2bf(f.y); u.z = f2bf(f.z); u.w = f2bf(f.w);
        *reinterpret_cast<ushort4*>(d + i) = u;
    }
}

// ---------------- QKV projection GEMM ----------------
// 256x256 tile, BK=64, 8 waves (2M x 4N), depth-2 counted-vmcnt pipeline:
//   Stage(t)   : 8 global_load_lds per wave into buf[t&1] (linear LDS dest,
//                source column pre-swizzled: col ^= (row&7)*8)
//   loop t     : s_waitcnt vmcnt(8)  [Stage(t) landed, Stage(t+1) in flight]
//                s_barrier; compute(t); s_barrier; Stage(t+2)
// No vmcnt(0) drain in the main loop (the round-5/6 bottleneck). ds_read
// applies the same XOR involution -> conflict-free b128 reads.
__global__ __launch_bounds__(512, 2) void qkv_gemm(
    const unsigned short* __restrict__ xb,   // [8192][768] bf16
    const unsigned short* __restrict__ wb,   // [2304][768] bf16
    const float* __restrict__ bias,          // [2304] f32
    unsigned short* __restrict__ qo,
    unsigned short* __restrict__ ko,
    unsigned short* __restrict__ vto)
{
    __shared__ unsigned short A0[256 * 64];
    __shared__ unsigned short B0[256 * 64];
    __shared__ unsigned short A1[256 * 64];
    __shared__ unsigned short B1[256 * 64];
    const int tid = threadIdx.x;
    const int lane = tid & 63;
    const int w = tid >> 6;
    const int lr = lane >> 4, lc = lane & 15;

    // XCD-aware swizzle: 288 blocks, 288%8==0 -> 36 consecutive per XCD,
    // bn-major so each XCD's slice shares 4 m-rows (x slice 1.5 MB -> L2-fit)
    const int swz = (blockIdx.x & 7) * 36 + (blockIdx.x >> 3);
    const int bn = swz % 9, bm = swz / 9;
    const int m0 = bm * 256;
    const int n0 = bn * 256;
    const int wrow = (w >> 2) * 128;   // 2 M-waves
    const int wcol = (w & 3) * 64;     // 4 N-waves
    const int wofs = w * 512;          // staging LDS base (elems) per wave

    f32x4 acc[8][4] = {};

#define WAIT8 asm volatile("s_waitcnt vmcnt(8)" ::: "memory")
#define WAIT0 asm volatile("s_waitcnt vmcnt(0)" ::: "memory")
#define BAR   do { __builtin_amdgcn_s_barrier(); __builtin_amdgcn_sched_barrier(0); } while (0)

    // Stage one K-tile (A 256x64 + B 256x64) -> 4+4 gload16 per thread.
    // chunk ca = j*512+tid; row = ca>>3; src col pre-swizzled by (row&7)*8.
#define STAGE(KT, LA, LB)                                                 \
    do {                                                                  \
        _Pragma("unroll")                                                 \
        for (int j = 0; j < 4; ++j) {                                     \
            int ca = j * 512 + tid;                                       \
            int ra = ca >> 3;                                             \
            int csw = ((ca & 7) ^ (ra & 7)) * 8;                          \
            gload16(xb + (size_t)(m0 + ra) * CSZ + (KT) + csw, (LA) + j * 4096 + wofs); \
            gload16(wb + (size_t)(n0 + ra) * CSZ + (KT) + csw, (LB) + j * 4096 + wofs); \
        }                                                                 \
    } while (0)

#define COMPUTE(LA, LB)                                                   \
    do {                                                                  \
        short8 bfr[4][2];                                                 \
        _Pragma("unroll")                                                 \
        for (int ni = 0; ni < 4; ++ni)                                    \
            _Pragma("unroll")                                             \
            for (int ks = 0; ks < 2; ++ks)                                \
                bfr[ni][ks] = *reinterpret_cast<const short8*>(           \
                    (LB) + (wcol + ni * 16 + lc) * 64 +                   \
                    ((ks * 32 + lr * 8) ^ ((lc & 7) * 8)));               \
        __builtin_amdgcn_s_setprio(1);                                    \
        _Pragma("unroll")                                                 \
        for (int mi = 0; mi < 8; ++mi) {                                  \
            short8 af0 = *reinterpret_cast<const short8*>(                \
                (LA) + (wrow + mi * 16 + lc) * 64 + ((lr * 8) ^ ((lc & 7) * 8))); \
            short8 af1 = *reinterpret_cast<const short8*>(                \
                (LA) + (wrow + mi * 16 + lc) * 64 + ((32 + lr * 8) ^ ((lc & 7) * 8))); \
            _Pragma("unroll")                                             \
            for (int ni = 0; ni < 4; ++ni) {                              \
                acc[mi][ni] = __builtin_amdgcn_mfma_f32_16x16x32_bf16(    \
                    af0, bfr[ni][0], acc[mi][ni], 0, 0, 0);               \
                acc[mi][ni] = __builtin_amdgcn_mfma_f32_16x16x32_bf16(    \
                    af1, bfr[ni][1], acc[mi][ni], 0, 0, 0);               \
            }                                                             \
        }                                                                 \
        __builtin_amdgcn_s_setprio(0);                                    \
    } while (0)

    // prologue: tiles 0,1 in flight
    STAGE(0, A0, B0);
    STAGE(64, A1, B1);
    // main loop: t = 0..9 (12 K-tiles total, K=768)
    #pragma unroll 1
    for (int tt = 0; tt < 5; ++tt) {
        const int kt = tt * 128;
        WAIT8; BAR; COMPUTE(A0, B0); BAR; STAGE(kt + 128, A0, B0);
        WAIT8; BAR; COMPUTE(A1, B1); BAR; STAGE(kt + 192, A1, B1);
    }
    WAIT8; BAR; COMPUTE(A0, B0);   // t=10
    WAIT0; BAR; COMPUTE(A1, B1);   // t=11 (final drain)
#undef STAGE
#undef COMPUTE
#undef WAIT8
#undef WAIT0
#undef BAR

    // epilogue: 256 cols = uniform q/k/v section per block (256 | 768)
    const int sec = n0 / CSZ;
    const int nb = n0 - sec * CSZ;
    #pragma unroll
    for (int ni = 0; ni < 4; ++ni) {
        int ncol = wcol + ni * 16 + lc;     // 0..255 within block
        int nn = nb + ncol;                 // 0..767 within section
        float badd = bias[n0 + ncol];
        int h = nn >> 6, d = nn & 63;
        #pragma unroll
        for (int mi = 0; mi < 8; ++mi) {
            #pragma unroll
            for (int r = 0; r < 4; ++r) {
                int m = m0 + wrow + mi * 16 + lr * 4 + r;
                int bb = m >> 10, t = m & 1023;
                int plane = bb * N_HEADS + h;
                float v = acc[mi][ni][r] + badd;
                if (sec == 0)
                    qo[((size_t)plane * TSZ + t) * HD + d] = f2bf(v * 0.125f);
                else if (sec == 1)
                    ko[((size_t)plane * TSZ + t) * HD + d] = f2bf(v);
                else
                    vto[((size_t)plane * HD + d) * TSZ + t] = f2bf(v);
            }
        }
    }
}

// ---------------- causal-ReLU attention ----------------
// 2 waves per block; wave 0 handles q-tile j, wave 1 handles q-tile 15-j
// (perfect balance: 17 K-tile steps per block). Per wave:
// S^T = mfma(K_frag, Q_frag) -> mask+ReLU -> packed bf16 via cvt_pk ->
// ds_write_b64 -> PV from LDS S-frags and global v^T frags.
__global__ __launch_bounds__(128, 2) void attn_kernel(
    const unsigned short* __restrict__ q,    // [96][1024][64] bf16 (pre-scaled)
    const unsigned short* __restrict__ k,    // [96][1024][64] bf16
    const unsigned short* __restrict__ vt,   // [96][64][1024] bf16
    float* __restrict__ out)                 // [8][1024][768] f32
{
    __shared__ unsigned short smem[2 * 64 * LDA];
    const int wid = threadIdx.x >> 6;
    const int lane = threadIdx.x & 63;
    const int lr = lane >> 4, lc = lane & 15;
    const int qw = wid == 0 ? blockIdx.x : 15 - blockIdx.x;   // 0..15
    const int bh = blockIdx.y;               // 0..95
    const int b = bh / N_HEADS, h = bh - b * N_HEADS;
    const size_t base = (size_t)bh * (TSZ * HD);
    const int qrow0 = qw * 64;
    unsigned short* sm = smem + wid * 64 * LDA;

    // Q fragments (MFMA B operand for the S^T trick)
    short8 aq[2][4];
    #pragma unroll
    for (int ks = 0; ks < 2; ++ks)
        #pragma unroll
        for (int qi = 0; qi < 4; ++qi)
            aq[ks][qi] = *reinterpret_cast<const short8*>(
                q + base + (size_t)(qrow0 + qi * 16 + lc) * HD + ks * 32 + lr * 8);

    f32x4 y[4][4] = {};

    for (int kt = 0; kt <= qw; ++kt) {
        const int kv0 = kt * 64;
        f32x4 st[4][4] = {};   // S^T fragments: rows kv, cols q
        #pragma unroll
        for (int ks = 0; ks < 2; ++ks) {
            short8 ak[4];
            #pragma unroll
            for (int ki = 0; ki < 4; ++ki)
                ak[ki] = *reinterpret_cast<const short8*>(
                    k + base + (size_t)(kv0 + ki * 16 + lc) * HD + ks * 32 + lr * 8);
            #pragma unroll
            for (int ki = 0; ki < 4; ++ki)
                #pragma unroll
                for (int qi = 0; qi < 4; ++qi)
                    st[ki][qi] = __builtin_amdgcn_mfma_f32_16x16x32_bf16(
                        ak[ki], aq[ks][qi], st[ki][qi], 0, 0, 0);
        }
        const bool diag = (kt == qw);
        #pragma unroll
        for (int ki = 0; ki < 4; ++ki) {
            #pragma unroll
            for (int qi = 0; qi < 4; ++qi) {
                float vv[4];
                #pragma unroll
                for (int r = 0; r < 4; ++r) {
                    float s = fmaxf(st[ki][qi][r], 0.0f);          // ReLU
                    if (diag && (ki * 16 + lr * 4 + r > qi * 16 + lc))
                        s = 0.0f;                                   // causal mask
                    vv[r] = s;
                }
                __hip_bfloat162 p0 = __float22bfloat162_rn(make_float2(vv[0], vv[1]));
                __hip_bfloat162 p1 = __float22bfloat162_rn(make_float2(vv[2], vv[3]));
                uint2 pk;
                pk.x = *reinterpret_cast<unsigned*>(&p0);
                pk.y = *reinterpret_cast<unsigned*>(&p1);
                // S[q][kv] layout: 4 consecutive kv per lane -> one b64 write
                *reinterpret_cast<uint2*>(
                    sm + (qi * 16 + lc) * LDA + ki * 16 + lr * 4) = pk;
            }
        }
        // PV: y[q][d] += S[q][kv] * V[kv][d]  (V via transposed vt[d][kv])
        #pragma unroll
        for (int ks = 0; ks < 2; ++ks) {
            short8 as[4], bv[4];
            #pragma unroll
            for (int qi = 0; qi < 4; ++qi)
                as[qi] = *reinterpret_cast<const short8*>(
                    sm + (qi * 16 + lc) * LDA + ks * 32 + lr * 8);
            #pragma unroll
            for (int di = 0; di < 4; ++di)
                bv[di] = *reinterpret_cast<const short8*>(
                    vt + (size_t)bh * (HD * TSZ) + (size_t)(di * 16 + lc) * TSZ
                       + kv0 + ks * 32 + lr * 8);
            #pragma unroll
            for (int qi = 0; qi < 4; ++qi)
                #pragma unroll
                for (int di = 0; di < 4; ++di)
                    y[qi][di] = __builtin_amdgcn_mfma_f32_16x16x32_bf16(
                        as[qi], bv[di], y[qi][di], 0, 0, 0);
        }
    }

    #pragma unroll
    for (int qi = 0; qi < 4; ++qi)
        #pragma unroll
        for (int di = 0; di < 4; ++di)
            #pragma unroll
            for (int r = 0; r < 4; ++r) {
                int t = qrow0 + qi * 16 + lr * 4 + r;
                int d = di * 16 + lc;
                out[((size_t)b * TSZ + t) * CSZ + h * HD + d] = y[qi][di][r];
            }
}

extern "C" void kernel_launch(void* const* d_in, const int* in_sizes, int n_in,
                              void* d_out, int out_size, void* d_ws, size_t ws_size,
                              hipStream_t stream) {
    const float* x    = (const float*)d_in[0];
    const float* W    = (const float*)d_in[1];
    const float* bias = (const float*)d_in[2];
    float* out = (float*)d_out;

    unsigned short* xb  = (unsigned short*)d_ws;                 // 8192*768
    unsigned short* wb  = xb + (size_t)MSZ * CSZ;                // 2304*768
    unsigned short* qo  = wb + (size_t)N3 * CSZ;                 // 96*1024*64
    unsigned short* ko  = qo + (size_t)MSZ * CSZ;
    unsigned short* vto = ko + (size_t)MSZ * CSZ;

    const int nx = MSZ * CSZ;   // 6291456
    const int nw = N3 * CSZ;    // 1769472
    cvt_f32_to_bf16<<<nx / 1024, 256, 0, stream>>>(x, xb, nx);
    cvt_f32_to_bf16<<<nw / 1024, 256, 0, stream>>>(W, wb, nw);
    qkv_gemm<<<dim3((MSZ / 256) * (N3 / 256)), 512, 0, stream>>>(xb, wb, bias, qo, ko, vto);
    attn_kernel<<<dim3(8, BSZ * N_HEADS), 128, 0, stream>>>(qo, ko, vto, out);
}